// Round 1
// baseline (5646.876 us; speedup 1.0000x reference)
//
#include <hip/hip_runtime.h>
#include <math.h>

// GATNet_MLP: 3x GAT(edge-attr) + MLP head + global mean pool. All fp32.
// N=50000 nodes, E=400000 edges, G=64 graphs.
// Algebraic notes:
//  - edge features e=ea@We only feed (e*att_e).sum(-1)  ==>  a_e = ea @ M, M[5,H]=sum_c We[:,h,c]*ae[h,c]
//  - segment-softmax max-shift dropped (w invariant; alphas are O(0.5), expf safe)

#define N_NODES 50000
#define N_EDGES 400000
#define N_GRAPH 64
#define DIN     128
#define NHC     256   // H*C for every layer
#define DOUT    32

// ---------------- GEMM: C[n,M] = A[n,K] @ B[K,M] (+bias) (+gelu) ----------------
#define BM 128
#define BN 64
#define BK 16

__global__ __launch_bounds__(256) void gemm_kernel(
    const float* __restrict__ A, const float* __restrict__ B,
    const float* __restrict__ bias, float* __restrict__ C,
    int nrow, int K, int M, int act)
{
    __shared__ float As[BK][BM + 4];   // +4 pad: store pattern lands 2-way (free)
    __shared__ float Bs[BK][BN];
    const int tid = threadIdx.x;
    const int tx = tid & 15, ty = tid >> 4;
    const int row0 = blockIdx.y * BM, col0 = blockIdx.x * BN;
    float acc[8][4];
#pragma unroll
    for (int i = 0; i < 8; i++)
#pragma unroll
        for (int j = 0; j < 4; j++) acc[i][j] = 0.f;

    for (int k0 = 0; k0 < K; k0 += BK) {
#pragma unroll
        for (int i = 0; i < 8; i++) {
            int idx = tid + i * 256;
            int r = idx >> 4, c = idx & 15;
            int gr = row0 + r;
            As[c][r] = (gr < nrow) ? A[(long)gr * K + k0 + c] : 0.f;
        }
#pragma unroll
        for (int i = 0; i < 4; i++) {
            int idx = tid + i * 256;
            int r = idx >> 6, c = idx & 63;
            int gc = col0 + c;
            Bs[r][c] = (gc < M) ? B[(long)(k0 + r) * M + gc] : 0.f;
        }
        __syncthreads();
#pragma unroll
        for (int k = 0; k < BK; k++) {
            float a[8], b[4];
#pragma unroll
            for (int i = 0; i < 4; i++) {
                a[i]     = As[k][ty * 4 + i];        // rows split {ty*4+i, 64+ty*4+i}:
                a[4 + i] = As[k][64 + ty * 4 + i];   // 2-way LDS alias only (free)
            }
#pragma unroll
            for (int j = 0; j < 4; j++) b[j] = Bs[k][tx * 4 + j];
#pragma unroll
            for (int i = 0; i < 8; i++)
#pragma unroll
                for (int j = 0; j < 4; j++) acc[i][j] += a[i] * b[j];
        }
        __syncthreads();
    }
#pragma unroll
    for (int i = 0; i < 8; i++) {
        int r = (i < 4) ? (ty * 4 + i) : (64 + ty * 4 + (i - 4));
        int gr = row0 + r;
        if (gr >= nrow) continue;
#pragma unroll
        for (int j = 0; j < 4; j++) {
            int gc = col0 + tx * 4 + j;
            if (gc >= M) continue;
            float v = acc[i][j];
            if (bias) v += bias[gc];
            if (act == 1) v = 0.5f * v * (1.f + erff(v * 0.7071067811865475f)); // exact gelu
            C[(long)gr * M + gc] = v;
        }
    }
}

// -------- per-node attention scalars: a_s[n,h] = <h[n,h,:], att_s[h,:]>, same a_d --------
__global__ __launch_bounds__(256) void asd_kernel(
    const float* __restrict__ h, const float* __restrict__ atts, const float* __restrict__ attd,
    float* __restrict__ asb, float* __restrict__ adb, int total, int H, int C)
{
    int i = blockIdx.x * 256 + threadIdx.x;
    if (i >= total) return;              // total = N*H
    int n = i / H, hh = i - n * H;
    const float4* hp = (const float4*)(h + (long)n * NHC + hh * C);
    const float4* sp = (const float4*)(atts + hh * C);
    const float4* dp = (const float4*)(attd + hh * C);
    float ss = 0.f, dd = 0.f;
    for (int c = 0; c < C / 4; c++) {
        float4 hv = hp[c], sv = sp[c], dv = dp[c];
        ss += hv.x * sv.x + hv.y * sv.y + hv.z * sv.z + hv.w * sv.w;
        dd += hv.x * dv.x + hv.y * dv.y + hv.z * dv.z + hv.w * dv.w;
    }
    asb[i] = ss; adb[i] = dd;
}

// -------- M[j,h] = sum_c We[j, h*C+c] * ae[h*C+c]  (5 x H, tiny) --------
__global__ void me_kernel(const float* __restrict__ We, const float* __restrict__ ae,
                          float* __restrict__ Me, int H, int C)
{
    int i = threadIdx.x;
    if (i >= 5 * H) return;
    int j = i / H, hh = i - j * H;
    float s = 0.f;
    for (int c = 0; c < C; c++) s += We[j * NHC + hh * C + c] * ae[hh * C + c];
    Me[i] = s;   // [j][h]
}

// -------- per edge: p = exp(leaky_relu(a_s[src]+a_d[dst]+a_e)); denom[dst] += p --------
__global__ __launch_bounds__(256) void edge_p_kernel(
    const int* __restrict__ ei, const float* __restrict__ ea,
    const float* __restrict__ asb, const float* __restrict__ adb,
    const float* __restrict__ Me, float* __restrict__ p, float* __restrict__ den,
    int E, int H)
{
    int e = blockIdx.x * 256 + threadIdx.x;
    if (e >= E) return;
    int src = ei[e], dst = ei[E + e];
    float a0 = ea[e * 5 + 0], a1 = ea[e * 5 + 1], a2 = ea[e * 5 + 2],
          a3 = ea[e * 5 + 3], a4 = ea[e * 5 + 4];
    for (int h = 0; h < H; h++) {
        float aeh = a0 * Me[0 * H + h] + a1 * Me[1 * H + h] + a2 * Me[2 * H + h]
                  + a3 * Me[3 * H + h] + a4 * Me[4 * H + h];
        float al = asb[src * H + h] + adb[dst * H + h] + aeh;
        al = (al >= 0.f) ? al : 0.2f * al;         // leaky_relu(0.2)
        float pv = expf(al);                        // max-shift dropped (invariant)
        p[(long)e * H + h] = pv;
        atomicAdd(&den[dst * H + h], pv);
    }
}

__global__ __launch_bounds__(256) void invden_kernel(float* __restrict__ den, int n)
{
    int i = blockIdx.x * 256 + threadIdx.x;
    if (i < n) den[i] = 1.0f / (den[i] + 1e-16f);
}

// -------- scatter: agg[dst, c] += h[src, c] * w(e, head(c)) ; 64 lanes/edge, float4 --------
__global__ __launch_bounds__(256) void scatter_kernel(
    const int* __restrict__ ei, const float* __restrict__ p, const float* __restrict__ invden,
    const float* __restrict__ h, float* __restrict__ agg, int E, int H, int clog2)
{
    int t = blockIdx.x * 256 + threadIdx.x;
    int e = t >> 6;
    if (e >= E) return;
    int lane = t & 63;
    int c0 = lane * 4;                 // 0..252
    int src = ei[e], dst = ei[E + e];
    int head = c0 >> clog2;            // C=32 -> 5 ; C=256 -> 8
    float w = p[(long)e * H + head] * invden[dst * H + head];
    const float4 hv = *(const float4*)(h + (long)src * NHC + c0);
    float* ap = agg + (long)dst * NHC + c0;
    atomicAdd(ap + 0, hv.x * w);
    atomicAdd(ap + 1, hv.y * w);
    atomicAdd(ap + 2, hv.z * w);
    atomicAdd(ap + 3, hv.w * w);
}

// -------- x = elu(agg + bias) in place --------
__global__ __launch_bounds__(256) void elu_bias_kernel(
    float* __restrict__ x, const float* __restrict__ bias, int total)
{
    int i = blockIdx.x * 256 + threadIdx.x;
    if (i >= total) return;
    int c = i & (NHC - 1);
    float v = x[i] + bias[c];
    x[i] = (v > 0.f) ? v : expm1f(v);
}

// -------- pooling --------
__global__ __launch_bounds__(256) void pool_kernel(
    const float* __restrict__ f2, const int* __restrict__ batch,
    float* __restrict__ sums, float* __restrict__ cnt, int N)
{
    int i = blockIdx.x * 256 + threadIdx.x;
    if (i >= N * DOUT) return;
    int n = i >> 5, c = i & 31;
    int b = batch[n];
    atomicAdd(&sums[b * DOUT + c], f2[i]);
    if (c == 0) atomicAdd(&cnt[b], 1.0f);
}

__global__ void pool_div_kernel(const float* __restrict__ sums, const float* __restrict__ cnt,
                                float* __restrict__ out)
{
    int i = blockIdx.x * 256 + threadIdx.x;
    if (i >= N_GRAPH * DOUT) return;
    out[i] = sums[i] / fmaxf(cnt[i >> 5], 1.0f);
}

extern "C" void kernel_launch(void* const* d_in, const int* in_sizes, int n_in,
                              void* d_out, int out_size, void* d_ws, size_t ws_size,
                              hipStream_t stream)
{
    const float* x    = (const float*)d_in[0];
    const int*   ei   = (const int*)  d_in[1];
    const float* ea   = (const float*)d_in[2];
    const int*   bat  = (const int*)  d_in[3];
    const float* W[3]   = {(const float*)d_in[4],  (const float*)d_in[10], (const float*)d_in[16]};
    const float* Asl[3] = {(const float*)d_in[5],  (const float*)d_in[11], (const float*)d_in[17]};
    const float* Adl[3] = {(const float*)d_in[6],  (const float*)d_in[12], (const float*)d_in[18]};
    const float* Wel[3] = {(const float*)d_in[7],  (const float*)d_in[13], (const float*)d_in[19]};
    const float* Ael[3] = {(const float*)d_in[8],  (const float*)d_in[14], (const float*)d_in[20]};
    const float* Bil[3] = {(const float*)d_in[9],  (const float*)d_in[15], (const float*)d_in[21]};
    const float* fcW1 = (const float*)d_in[22];
    const float* fcb1 = (const float*)d_in[23];
    const float* fcW2 = (const float*)d_in[24];
    const float* fcb2 = (const float*)d_in[25];

    // workspace layout (floats); total ~31.6M floats = ~126.5 MB
    float* ws   = (float*)d_ws;
    float* h    = ws;                                   // N*256
    float* agg  = h    + (size_t)N_NODES * NHC;         // N*256 (also x_next after elu)
    float* p    = agg  + (size_t)N_NODES * NHC;         // E*8
    float* asb  = p    + (size_t)N_EDGES * 8;           // N*8
    float* adb  = asb  + (size_t)N_NODES * 8;           // N*8
    float* den  = adb  + (size_t)N_NODES * 8;           // N*8
    float* Me   = den  + (size_t)N_NODES * 8;           // 5*8
    float* f2   = Me   + 64;                            // N*32
    float* sums = f2   + (size_t)N_NODES * DOUT;        // 64*32
    float* cnt  = sums + N_GRAPH * DOUT;                // 64  (contiguous with sums)

    const int Hs[3] = {8, 8, 1};
    const int Cs[3] = {32, 32, 256};
    const int CL[3] = {5, 5, 8};
    const int Ks[3] = {DIN, NHC, NHC};

    const dim3 ggrid(NHC / BN, (N_NODES + BM - 1) / BM);

    const float* cur = x;
    for (int l = 0; l < 3; l++) {
        const int H = Hs[l], C = Cs[l];
        const int nh = N_NODES * H;
        gemm_kernel<<<ggrid, 256, 0, stream>>>(cur, W[l], nullptr, h, N_NODES, Ks[l], NHC, 0);
        asd_kernel<<<(nh + 255) / 256, 256, 0, stream>>>(h, Asl[l], Adl[l], asb, adb, nh, H, C);
        me_kernel<<<1, 64, 0, stream>>>(Wel[l], Ael[l], Me, H, C);
        hipMemsetAsync(den, 0, (size_t)nh * 4, stream);
        edge_p_kernel<<<(N_EDGES + 255) / 256, 256, 0, stream>>>(ei, ea, asb, adb, Me, p, den, N_EDGES, H);
        invden_kernel<<<(nh + 255) / 256, 256, 0, stream>>>(den, nh);
        hipMemsetAsync(agg, 0, (size_t)N_NODES * NHC * 4, stream);
        scatter_kernel<<<(N_EDGES * 64) / 256, 256, 0, stream>>>(ei, p, den, h, agg, N_EDGES, H, CL[l]);
        elu_bias_kernel<<<N_NODES, 256, 0, stream>>>(agg, Bil[l], N_NODES * NHC);
        cur = agg;
    }

    // MLP head: f1 = gelu(x4@fcW1 + b) -> h ; f2 = f1@fcW2 + b
    gemm_kernel<<<ggrid, 256, 0, stream>>>(agg, fcW1, fcb1, h, N_NODES, NHC, NHC, 1);
    const dim3 g2(1, (N_NODES + BM - 1) / BM);
    gemm_kernel<<<g2, 256, 0, stream>>>(h, fcW2, fcb2, f2, N_NODES, NHC, DOUT, 0);

    // global mean pool
    hipMemsetAsync(sums, 0, (N_GRAPH * DOUT + N_GRAPH) * 4, stream);
    pool_kernel<<<(N_NODES * DOUT + 255) / 256, 256, 0, stream>>>(f2, bat, sums, cnt, N_NODES);
    pool_div_kernel<<<(N_GRAPH * DOUT + 255) / 256, 256, 0, stream>>>(sums, cnt, (float*)d_out);
}

// Round 2
// 1426.252 us; speedup vs baseline: 3.9592x; 3.9592x over previous
//
#include <hip/hip_runtime.h>
#include <math.h>

// GATNet_MLP: 3x GAT(edge-attr) + MLP head + global mean pool. All fp32.
// R2: dst-CSR built per call (atomic count + block scan + fill), then fully
// fused atomic-free aggregation: out[n,c] = elu( (sum_e p_e*h[src_e,c]) / (sum_e p_e) + bias )
// (normalization commutes with the edge sum; softmax max-shift dropped: w invariant, |alpha|~O(0.5)).
// Edge-feature GEMM collapsed: a_e = ea @ Me, Me[5,H] = sum_c We[:,h,c]*ae[h,c].

#define N_NODES 50000
#define N_EDGES 400000
#define N_GRAPH 64
#define DIN     128
#define NHC     256
#define DOUT    32

// ---------------- GEMM: C[n,M] = A[n,K] @ B[K,M] (+bias) (+gelu) ----------------
#define BM 128
#define BN 64
#define BK 16

__global__ __launch_bounds__(256) void gemm_kernel(
    const float* __restrict__ A, const float* __restrict__ B,
    const float* __restrict__ bias, float* __restrict__ C,
    int nrow, int K, int M, int act)
{
    __shared__ float As[BK][BM + 4];
    __shared__ float Bs[BK][BN];
    const int tid = threadIdx.x;
    const int tx = tid & 15, ty = tid >> 4;
    const int row0 = blockIdx.y * BM, col0 = blockIdx.x * BN;
    float acc[8][4];
#pragma unroll
    for (int i = 0; i < 8; i++)
#pragma unroll
        for (int j = 0; j < 4; j++) acc[i][j] = 0.f;

    for (int k0 = 0; k0 < K; k0 += BK) {
#pragma unroll
        for (int i = 0; i < 8; i++) {
            int idx = tid + i * 256;
            int r = idx >> 4, c = idx & 15;
            int gr = row0 + r;
            As[c][r] = (gr < nrow) ? A[(long)gr * K + k0 + c] : 0.f;
        }
#pragma unroll
        for (int i = 0; i < 4; i++) {
            int idx = tid + i * 256;
            int r = idx >> 6, c = idx & 63;
            int gc = col0 + c;
            Bs[r][c] = (gc < M) ? B[(long)(k0 + r) * M + gc] : 0.f;
        }
        __syncthreads();
#pragma unroll
        for (int k = 0; k < BK; k++) {
            float a[8], b[4];
#pragma unroll
            for (int i = 0; i < 4; i++) {
                a[i]     = As[k][ty * 4 + i];
                a[4 + i] = As[k][64 + ty * 4 + i];
            }
#pragma unroll
            for (int j = 0; j < 4; j++) b[j] = Bs[k][tx * 4 + j];
#pragma unroll
            for (int i = 0; i < 8; i++)
#pragma unroll
                for (int j = 0; j < 4; j++) acc[i][j] += a[i] * b[j];
        }
        __syncthreads();
    }
#pragma unroll
    for (int i = 0; i < 8; i++) {
        int r = (i < 4) ? (ty * 4 + i) : (64 + ty * 4 + (i - 4));
        int gr = row0 + r;
        if (gr >= nrow) continue;
#pragma unroll
        for (int j = 0; j < 4; j++) {
            int gc = col0 + tx * 4 + j;
            if (gc >= M) continue;
            float v = acc[i][j];
            if (bias) v += bias[gc];
            if (act == 1) v = 0.5f * v * (1.f + erff(v * 0.7071067811865475f));
            C[(long)gr * M + gc] = v;
        }
    }
}

// -------- per-node attention scalars --------
__global__ __launch_bounds__(256) void asd_kernel(
    const float* __restrict__ h, const float* __restrict__ atts, const float* __restrict__ attd,
    float* __restrict__ asb, float* __restrict__ adb, int total, int H, int C)
{
    int i = blockIdx.x * 256 + threadIdx.x;
    if (i >= total) return;              // total = N*H
    int n = i / H, hh = i - n * H;
    const float4* hp = (const float4*)(h + (long)n * NHC + hh * C);
    const float4* sp = (const float4*)(atts + hh * C);
    const float4* dp = (const float4*)(attd + hh * C);
    float ss = 0.f, dd = 0.f;
    for (int c = 0; c < C / 4; c++) {
        float4 hv = hp[c], sv = sp[c], dv = dp[c];
        ss += hv.x * sv.x + hv.y * sv.y + hv.z * sv.z + hv.w * sv.w;
        dd += hv.x * dv.x + hv.y * dv.y + hv.z * dv.z + hv.w * dv.w;
    }
    asb[i] = ss; adb[i] = dd;
}

// -------- Me[j,h] = sum_c We[j, h*C+c] * ae[h*C+c]  (5 x H, tiny) --------
__global__ void me_kernel(const float* __restrict__ We, const float* __restrict__ ae,
                          float* __restrict__ Me, int H, int C)
{
    int i = threadIdx.x;
    if (i >= 5 * H) return;
    int j = i / H, hh = i - j * H;
    float s = 0.f;
    for (int c = 0; c < C; c++) s += We[j * NHC + hh * C + c] * ae[hh * C + c];
    Me[i] = s;
}

// ================= CSR build (per call; graph-capture safe) =================
__global__ __launch_bounds__(256) void count_kernel(
    const int* __restrict__ ei, int* __restrict__ deg, int E)
{
    int e = blockIdx.x * 256 + threadIdx.x;
    if (e < E) atomicAdd(&deg[ei[E + e]], 1);
}

// block-level exclusive scan (256/block) + per-block totals
__global__ __launch_bounds__(256) void scan_block_kernel(
    const int* __restrict__ deg, int* __restrict__ rowstart, int* __restrict__ partial, int n)
{
    __shared__ int s[256];
    int i = blockIdx.x * 256 + threadIdx.x;
    int v = (i < n) ? deg[i] : 0;
    s[threadIdx.x] = v;
    __syncthreads();
    for (int off = 1; off < 256; off <<= 1) {
        int t = (threadIdx.x >= off) ? s[threadIdx.x - off] : 0;
        __syncthreads();
        s[threadIdx.x] += t;
        __syncthreads();
    }
    if (i < n) rowstart[i] = s[threadIdx.x] - v;   // exclusive
    if (threadIdx.x == 255) partial[blockIdx.x] = s[255];
}

__global__ __launch_bounds__(256) void scan_partial_kernel(int* __restrict__ partial, int nb)
{
    __shared__ int s[256];
    int v = (threadIdx.x < nb) ? partial[threadIdx.x] : 0;
    s[threadIdx.x] = v;
    __syncthreads();
    for (int off = 1; off < 256; off <<= 1) {
        int t = (threadIdx.x >= off) ? s[threadIdx.x - off] : 0;
        __syncthreads();
        s[threadIdx.x] += t;
        __syncthreads();
    }
    if (threadIdx.x < nb) partial[threadIdx.x] = s[threadIdx.x] - v;  // exclusive
}

__global__ __launch_bounds__(256) void scan_add_kernel(
    int* __restrict__ rowstart, const int* __restrict__ partial, int* __restrict__ cursor,
    int n, int E)
{
    int i = blockIdx.x * 256 + threadIdx.x;
    if (i < n) {
        int v = rowstart[i] + partial[blockIdx.x];
        rowstart[i] = v;
        cursor[i] = v;          // cursor copy fused here
    }
    if (i == 0) rowstart[n] = E;
}

__global__ __launch_bounds__(256) void fill_kernel(
    const int* __restrict__ ei, int* __restrict__ cursor,
    int* __restrict__ csr_src, int* __restrict__ csr_eid, int E)
{
    int e = blockIdx.x * 256 + threadIdx.x;
    if (e >= E) return;
    int dst = ei[E + e];
    int pos = atomicAdd(&cursor[dst], 1);
    csr_src[pos] = ei[e];
    csr_eid[pos] = e;
}

// ========== fused GAT aggregation: 1 wave per dst node, 4 ch/lane ==========
__global__ __launch_bounds__(256) void gat_agg_kernel(
    const int* __restrict__ rowstart, const int* __restrict__ csr_src, const int* __restrict__ csr_eid,
    const float* __restrict__ ea, const float* __restrict__ asb, const float* __restrict__ adb,
    const float* __restrict__ Me, const float* __restrict__ h, const float* __restrict__ bias,
    float* __restrict__ out, int H, int clog2)
{
    int node = blockIdx.x * 4 + (threadIdx.x >> 6);
    if (node >= N_NODES) return;
    int lane = threadIdx.x & 63;
    int c0 = lane * 4;
    int head = c0 >> clog2;                  // C=32 -> >>5 ; C=256 -> >>8 (head 0)
    float Mh0 = Me[0 * H + head], Mh1 = Me[1 * H + head], Mh2 = Me[2 * H + head],
          Mh3 = Me[3 * H + head], Mh4 = Me[4 * H + head];
    float adn = adb[node * H + head];
    int beg = rowstart[node], end = rowstart[node + 1];
    float ax = 0.f, ay = 0.f, az = 0.f, aw = 0.f, den = 0.f;
    for (int i = beg; i < end; i++) {
        int src = csr_src[i];
        int eid = csr_eid[i];
        const float* eap = ea + (long)eid * 5;
        float aeh = eap[0] * Mh0 + eap[1] * Mh1 + eap[2] * Mh2 + eap[3] * Mh3 + eap[4] * Mh4;
        float al = asb[src * H + head] + adn + aeh;
        al = fmaxf(al, 0.2f * al);           // leaky_relu(0.2)
        float pv = expf(al);                 // max-shift dropped (invariant)
        den += pv;
        const float4 hv = *(const float4*)(h + (long)src * NHC + c0);
        ax += pv * hv.x; ay += pv * hv.y; az += pv * hv.z; aw += pv * hv.w;
    }
    float w = 1.0f / (den + 1e-16f);
    const float4 bv = *(const float4*)(bias + c0);
    float4 v;
    v.x = ax * w + bv.x;  v.y = ay * w + bv.y;
    v.z = az * w + bv.z;  v.w = aw * w + bv.w;
    v.x = (v.x > 0.f) ? v.x : expm1f(v.x);
    v.y = (v.y > 0.f) ? v.y : expm1f(v.y);
    v.z = (v.z > 0.f) ? v.z : expm1f(v.z);
    v.w = (v.w > 0.f) ? v.w : expm1f(v.w);
    *(float4*)(out + (long)node * NHC + c0) = v;
}

// -------- pooling --------
__global__ __launch_bounds__(256) void pool_kernel(
    const float* __restrict__ f2, const int* __restrict__ batch,
    float* __restrict__ sums, float* __restrict__ cnt, int N)
{
    int i = blockIdx.x * 256 + threadIdx.x;
    if (i >= N * DOUT) return;
    int n = i >> 5, c = i & 31;
    int b = batch[n];
    atomicAdd(&sums[b * DOUT + c], f2[i]);
    if (c == 0) atomicAdd(&cnt[b], 1.0f);
}

__global__ void pool_div_kernel(const float* __restrict__ sums, const float* __restrict__ cnt,
                                float* __restrict__ out)
{
    int i = blockIdx.x * 256 + threadIdx.x;
    if (i >= N_GRAPH * DOUT) return;
    out[i] = sums[i] / fmaxf(cnt[i >> 5], 1.0f);
}

extern "C" void kernel_launch(void* const* d_in, const int* in_sizes, int n_in,
                              void* d_out, int out_size, void* d_ws, size_t ws_size,
                              hipStream_t stream)
{
    const float* x    = (const float*)d_in[0];
    const int*   ei   = (const int*)  d_in[1];
    const float* ea   = (const float*)d_in[2];
    const int*   bat  = (const int*)  d_in[3];
    const float* W[3]   = {(const float*)d_in[4],  (const float*)d_in[10], (const float*)d_in[16]};
    const float* Asl[3] = {(const float*)d_in[5],  (const float*)d_in[11], (const float*)d_in[17]};
    const float* Adl[3] = {(const float*)d_in[6],  (const float*)d_in[12], (const float*)d_in[18]};
    const float* Wel[3] = {(const float*)d_in[7],  (const float*)d_in[13], (const float*)d_in[19]};
    const float* Ael[3] = {(const float*)d_in[8],  (const float*)d_in[14], (const float*)d_in[20]};
    const float* Bil[3] = {(const float*)d_in[9],  (const float*)d_in[15], (const float*)d_in[21]};
    const float* fcW1 = (const float*)d_in[22];
    const float* fcb1 = (const float*)d_in[23];
    const float* fcW2 = (const float*)d_in[24];
    const float* fcb2 = (const float*)d_in[25];

    // workspace layout (4B elems)
    float* ws   = (float*)d_ws;
    float* h    = ws;                                   // N*256
    float* xbuf = h    + (size_t)N_NODES * NHC;         // N*256 (layer outputs)
    float* asb  = xbuf + (size_t)N_NODES * NHC;         // N*8
    float* adb  = asb  + (size_t)N_NODES * 8;           // N*8
    float* Me   = adb  + (size_t)N_NODES * 8;           // 64
    float* f2   = Me   + 64;                            // N*32
    float* sums = f2   + (size_t)N_NODES * DOUT;        // 64*32
    float* cnt  = sums + N_GRAPH * DOUT;                // 64
    int* deg      = (int*)(cnt + N_GRAPH);              // N
    int* rowstart = deg + N_NODES;                      // N+1
    int* cursor   = rowstart + N_NODES + 1;             // N
    int* partial  = cursor + N_NODES;                   // 256
    int* csr_src  = partial + 256;                      // E
    int* csr_eid  = csr_src + N_EDGES;                  // E

    const int NB = (N_NODES + 255) / 256;               // 196 scan blocks

    // ---- build dst-CSR (once per call) ----
    hipMemsetAsync(deg, 0, (size_t)N_NODES * 4, stream);
    count_kernel<<<(N_EDGES + 255) / 256, 256, 0, stream>>>(ei, deg, N_EDGES);
    scan_block_kernel<<<NB, 256, 0, stream>>>(deg, rowstart, partial, N_NODES);
    scan_partial_kernel<<<1, 256, 0, stream>>>(partial, NB);
    scan_add_kernel<<<NB, 256, 0, stream>>>(rowstart, partial, cursor, N_NODES, N_EDGES);
    fill_kernel<<<(N_EDGES + 255) / 256, 256, 0, stream>>>(ei, cursor, csr_src, csr_eid, N_EDGES);

    const int Hs[3] = {8, 8, 1};
    const int Cs[3] = {32, 32, 256};
    const int CL[3] = {5, 5, 8};
    const int Ks[3] = {DIN, NHC, NHC};

    const dim3 ggrid(NHC / BN, (N_NODES + BM - 1) / BM);

    const float* cur = x;
    for (int l = 0; l < 3; l++) {
        const int H = Hs[l], C = Cs[l];
        const int nh = N_NODES * H;
        gemm_kernel<<<ggrid, 256, 0, stream>>>(cur, W[l], nullptr, h, N_NODES, Ks[l], NHC, 0);
        asd_kernel<<<(nh + 255) / 256, 256, 0, stream>>>(h, Asl[l], Adl[l], asb, adb, nh, H, C);
        me_kernel<<<1, 64, 0, stream>>>(Wel[l], Ael[l], Me, H, C);
        gat_agg_kernel<<<(N_NODES + 3) / 4, 256, 0, stream>>>(
            rowstart, csr_src, csr_eid, ea, asb, adb, Me, h, Bil[l], xbuf, H, CL[l]);
        cur = xbuf;
    }

    // MLP head
    gemm_kernel<<<ggrid, 256, 0, stream>>>(xbuf, fcW1, fcb1, h, N_NODES, NHC, NHC, 1);
    const dim3 g2(1, (N_NODES + BM - 1) / BM);
    gemm_kernel<<<g2, 256, 0, stream>>>(h, fcW2, fcb2, f2, N_NODES, NHC, DOUT, 0);

    // global mean pool
    hipMemsetAsync(sums, 0, (N_GRAPH * DOUT + N_GRAPH) * 4, stream);
    pool_kernel<<<(N_NODES * DOUT + 255) / 256, 256, 0, stream>>>(f2, bat, sums, cnt, N_NODES);
    pool_div_kernel<<<(N_GRAPH * DOUT + 255) / 256, 256, 0, stream>>>(sums, cnt, (float*)d_out);
}

// Round 3
// 828.909 us; speedup vs baseline: 6.8124x; 1.7206x over previous
//
#include <hip/hip_runtime.h>
#include <math.h>

// GATNet_MLP R3: atomic-free CSR aggregation (R2) + fp16x2-split MFMA GEMMs +
// per-graph block-reduced pooling (batch is sorted).
// fp16x2 split: a = hi + lo (fp16 each); a*b = ah*bh + ah*bl + al*bh (drop ll, ~2^-22 rel).

#define N_NODES 50000
#define N_EDGES 400000
#define N_GRAPH 64
#define DIN     128
#define NHC     256
#define DOUT    32

typedef _Float16 f16x8 __attribute__((ext_vector_type(8)));
typedef _Float16 f16x4 __attribute__((ext_vector_type(4)));
typedef float    f32x4 __attribute__((ext_vector_type(4)));

// ================= fp16x2-split MFMA GEMM =================
// C[nrow, ncols] = A @ B, A given as fp16 planes [nrow][K], B as transposed
// fp16 planes [Npad][K] (Npad = gridDim.x*64). Block tile 128x64, 4 waves of 64x32.
// mode 0: C fp32 [nrow][256]           (no bias)
// mode 1: bias + exact gelu -> fp16 hi/lo planes Oh/Ol [nrow][256]
// mode 2: bias + fp32 C [nrow][ncols], cols masked to ncols
__global__ __launch_bounds__(256) void mfma_gemm_kernel(
    const _Float16* __restrict__ Ah, const _Float16* __restrict__ Al,
    const _Float16* __restrict__ Bh, const _Float16* __restrict__ Bl,
    const float* __restrict__ bias, float* __restrict__ C,
    _Float16* __restrict__ Oh, _Float16* __restrict__ Ol,
    int nrow, int K, int ncols, int mode)
{
    __shared__ __align__(16) _Float16 sAh[128][32];
    __shared__ __align__(16) _Float16 sAl[128][32];
    __shared__ __align__(16) _Float16 sBh[64][32];
    __shared__ __align__(16) _Float16 sBl[64][32];

    const int tid = threadIdx.x, lane = tid & 63, wid = tid >> 6;
    const int wm = wid & 1, wn = wid >> 1;
    const int row0 = blockIdx.y * 128, col0 = blockIdx.x * 64;
    const int rs = lane >> 2, kq = lane & 3;      // staging map: 16 rows x 4 chunks / wave
    const int frow = lane & 15, fk = (lane >> 4) * 8;  // fragment map

    f32x4 acc[4][2] = {};

    for (int k0 = 0; k0 < K; k0 += 32) {
        // ---- stage A: 2 passes x 2 planes ----
#pragma unroll
        for (int p = 0; p < 2; p++) {
            int r = p * 64 + wid * 16 + rs;
            int gr = row0 + r;
            long go = (long)gr * K + k0 + kq * 8;
            f16x8 vh = (gr < nrow) ? *(const f16x8*)(Ah + go) : (f16x8)0;
            f16x8 vl = (gr < nrow) ? *(const f16x8*)(Al + go) : (f16x8)0;
            *(f16x8*)&sAh[r][kq * 8] = vh;
            *(f16x8*)&sAl[r][kq * 8] = vl;
        }
        // ---- stage B: 1 pass x 2 planes (cols always in range: grid sized by Npad) ----
        {
            int n = wid * 16 + rs;
            long go = (long)(col0 + n) * K + k0 + kq * 8;
            *(f16x8*)&sBh[n][kq * 8] = *(const f16x8*)(Bh + go);
            *(f16x8*)&sBl[n][kq * 8] = *(const f16x8*)(Bl + go);
        }
        __syncthreads();

        f16x8 bh[2], bl[2];
#pragma unroll
        for (int nt = 0; nt < 2; nt++) {
            bh[nt] = *(const f16x8*)&sBh[wn * 32 + nt * 16 + frow][fk];
            bl[nt] = *(const f16x8*)&sBl[wn * 32 + nt * 16 + frow][fk];
        }
#pragma unroll
        for (int mt = 0; mt < 4; mt++) {
            f16x8 ah = *(const f16x8*)&sAh[wm * 64 + mt * 16 + frow][fk];
            f16x8 al = *(const f16x8*)&sAl[wm * 64 + mt * 16 + frow][fk];
#pragma unroll
            for (int nt = 0; nt < 2; nt++) {
                acc[mt][nt] = __builtin_amdgcn_mfma_f32_16x16x32_f16(ah, bh[nt], acc[mt][nt], 0, 0, 0);
                acc[mt][nt] = __builtin_amdgcn_mfma_f32_16x16x32_f16(ah, bl[nt], acc[mt][nt], 0, 0, 0);
                acc[mt][nt] = __builtin_amdgcn_mfma_f32_16x16x32_f16(al, bh[nt], acc[mt][nt], 0, 0, 0);
            }
        }
        __syncthreads();
    }

    // ---- epilogue ----  C/D layout: col = lane&15, row = (lane>>4)*4 + reg
    const int crow0 = row0 + wm * 64 + (lane >> 4) * 4;
    const int ccol0 = col0 + wn * 32 + (lane & 15);
#pragma unroll
    for (int mt = 0; mt < 4; mt++) {
#pragma unroll
        for (int nt = 0; nt < 2; nt++) {
            int col = ccol0 + nt * 16;
#pragma unroll
            for (int r = 0; r < 4; r++) {
                int row = crow0 + mt * 16 + r;
                if (row >= nrow) continue;
                float v = acc[mt][nt][r];
                if (mode == 0) {
                    C[(long)row * 256 + col] = v;
                } else if (mode == 1) {
                    v += bias[col];
                    v = 0.5f * v * (1.f + erff(v * 0.7071067811865475f));
                    _Float16 hh = (_Float16)v;
                    Oh[(long)row * 256 + col] = hh;
                    Ol[(long)row * 256 + col] = (_Float16)(v - (float)hh);
                } else {
                    if (col < ncols) {
                        v += bias[col];
                        C[(long)row * ncols + col] = v;
                    }
                }
            }
        }
    }
}

// -------- split fp32 -> fp16 hi/lo planes (for x) --------
__global__ __launch_bounds__(256) void split_kernel(
    const float* __restrict__ in, _Float16* __restrict__ oh, _Float16* __restrict__ ol, int n4)
{
    int i = blockIdx.x * 256 + threadIdx.x;
    if (i >= n4) return;
    float4 v = ((const float4*)in)[i];
    f16x4 h, l;
    h[0] = (_Float16)v.x; l[0] = (_Float16)(v.x - (float)h[0]);
    h[1] = (_Float16)v.y; l[1] = (_Float16)(v.y - (float)h[1]);
    h[2] = (_Float16)v.z; l[2] = (_Float16)(v.z - (float)h[2]);
    h[3] = (_Float16)v.w; l[3] = (_Float16)(v.w - (float)h[3]);
    *(f16x4*)(oh + (long)i * 4) = h;
    *(f16x4*)(ol + (long)i * 4) = l;
}

// -------- transpose + split weights: W[K][N] fp32 -> Bt planes [Npad][K] fp16 --------
__global__ __launch_bounds__(256) void tsplit_kernel(
    const float* __restrict__ W, _Float16* __restrict__ Bh, _Float16* __restrict__ Bl,
    int K, int N, int Npad)
{
    int id = blockIdx.x * 256 + threadIdx.x;
    if (id >= Npad * K) return;
    int n = id / K, k = id - n * K;
    float v = (n < N) ? W[(long)k * N + n] : 0.f;
    _Float16 h = (_Float16)v;
    Bh[id] = h;
    Bl[id] = (_Float16)(v - (float)h);
}

// -------- per-node attention scalars --------
__global__ __launch_bounds__(256) void asd_kernel(
    const float* __restrict__ h, const float* __restrict__ atts, const float* __restrict__ attd,
    float* __restrict__ asb, float* __restrict__ adb, int total, int H, int C)
{
    int i = blockIdx.x * 256 + threadIdx.x;
    if (i >= total) return;              // total = N*H
    int n = i / H, hh = i - n * H;
    const float4* hp = (const float4*)(h + (long)n * NHC + hh * C);
    const float4* sp = (const float4*)(atts + hh * C);
    const float4* dp = (const float4*)(attd + hh * C);
    float ss = 0.f, dd = 0.f;
    for (int c = 0; c < C / 4; c++) {
        float4 hv = hp[c], sv = sp[c], dv = dp[c];
        ss += hv.x * sv.x + hv.y * sv.y + hv.z * sv.z + hv.w * sv.w;
        dd += hv.x * dv.x + hv.y * dv.y + hv.z * dv.z + hv.w * dv.w;
    }
    asb[i] = ss; adb[i] = dd;
}

// -------- Me[j,h] = sum_c We[j, h*C+c] * ae[h*C+c] --------
__global__ void me_kernel(const float* __restrict__ We, const float* __restrict__ ae,
                          float* __restrict__ Me, int H, int C)
{
    int i = threadIdx.x;
    if (i >= 5 * H) return;
    int j = i / H, hh = i - j * H;
    float s = 0.f;
    for (int c = 0; c < C; c++) s += We[j * NHC + hh * C + c] * ae[hh * C + c];
    Me[i] = s;
}

// ================= CSR build =================
__global__ __launch_bounds__(256) void count_kernel(
    const int* __restrict__ ei, int* __restrict__ deg, int E)
{
    int e = blockIdx.x * 256 + threadIdx.x;
    if (e < E) atomicAdd(&deg[ei[E + e]], 1);
}

__global__ __launch_bounds__(256) void scan_block_kernel(
    const int* __restrict__ deg, int* __restrict__ rowstart, int* __restrict__ partial, int n)
{
    __shared__ int s[256];
    int i = blockIdx.x * 256 + threadIdx.x;
    int v = (i < n) ? deg[i] : 0;
    s[threadIdx.x] = v;
    __syncthreads();
    for (int off = 1; off < 256; off <<= 1) {
        int t = (threadIdx.x >= off) ? s[threadIdx.x - off] : 0;
        __syncthreads();
        s[threadIdx.x] += t;
        __syncthreads();
    }
    if (i < n) rowstart[i] = s[threadIdx.x] - v;
    if (threadIdx.x == 255) partial[blockIdx.x] = s[255];
}

__global__ __launch_bounds__(256) void scan_partial_kernel(int* __restrict__ partial, int nb)
{
    __shared__ int s[256];
    int v = (threadIdx.x < nb) ? partial[threadIdx.x] : 0;
    s[threadIdx.x] = v;
    __syncthreads();
    for (int off = 1; off < 256; off <<= 1) {
        int t = (threadIdx.x >= off) ? s[threadIdx.x - off] : 0;
        __syncthreads();
        s[threadIdx.x] += t;
        __syncthreads();
    }
    if (threadIdx.x < nb) partial[threadIdx.x] = s[threadIdx.x] - v;
}

__global__ __launch_bounds__(256) void scan_add_kernel(
    int* __restrict__ rowstart, const int* __restrict__ partial, int* __restrict__ cursor,
    int n, int E)
{
    int i = blockIdx.x * 256 + threadIdx.x;
    if (i < n) {
        int v = rowstart[i] + partial[blockIdx.x];
        rowstart[i] = v;
        cursor[i] = v;
    }
    if (i == 0) rowstart[n] = E;
}

__global__ __launch_bounds__(256) void fill_kernel(
    const int* __restrict__ ei, int* __restrict__ cursor,
    int* __restrict__ csr_src, int* __restrict__ csr_eid, int E)
{
    int e = blockIdx.x * 256 + threadIdx.x;
    if (e >= E) return;
    int dst = ei[E + e];
    int pos = atomicAdd(&cursor[dst], 1);
    csr_src[pos] = ei[e];
    csr_eid[pos] = e;
}

// ========== fused GAT aggregation -> fp16 hi/lo planes ==========
__global__ __launch_bounds__(256) void gat_agg_kernel(
    const int* __restrict__ rowstart, const int* __restrict__ csr_src, const int* __restrict__ csr_eid,
    const float* __restrict__ ea, const float* __restrict__ asb, const float* __restrict__ adb,
    const float* __restrict__ Me, const float* __restrict__ h, const float* __restrict__ bias,
    _Float16* __restrict__ Oh, _Float16* __restrict__ Ol, int H, int clog2)
{
    int node = blockIdx.x * 4 + (threadIdx.x >> 6);
    if (node >= N_NODES) return;
    int lane = threadIdx.x & 63;
    int c0 = lane * 4;
    int head = c0 >> clog2;
    float Mh0 = Me[0 * H + head], Mh1 = Me[1 * H + head], Mh2 = Me[2 * H + head],
          Mh3 = Me[3 * H + head], Mh4 = Me[4 * H + head];
    float adn = adb[node * H + head];
    int beg = rowstart[node], end = rowstart[node + 1];
    float ax = 0.f, ay = 0.f, az = 0.f, aw = 0.f, den = 0.f;
    for (int i = beg; i < end; i++) {
        int src = csr_src[i];
        int eid = csr_eid[i];
        const float* eap = ea + (long)eid * 5;
        float aeh = eap[0] * Mh0 + eap[1] * Mh1 + eap[2] * Mh2 + eap[3] * Mh3 + eap[4] * Mh4;
        float al = asb[src * H + head] + adn + aeh;
        al = fmaxf(al, 0.2f * al);
        float pv = expf(al);
        den += pv;
        const float4 hv = *(const float4*)(h + (long)src * NHC + c0);
        ax += pv * hv.x; ay += pv * hv.y; az += pv * hv.z; aw += pv * hv.w;
    }
    float w = 1.0f / (den + 1e-16f);
    const float4 bv = *(const float4*)(bias + c0);
    float4 v;
    v.x = ax * w + bv.x;  v.y = ay * w + bv.y;
    v.z = az * w + bv.z;  v.w = aw * w + bv.w;
    v.x = (v.x > 0.f) ? v.x : expm1f(v.x);
    v.y = (v.y > 0.f) ? v.y : expm1f(v.y);
    v.z = (v.z > 0.f) ? v.z : expm1f(v.z);
    v.w = (v.w > 0.f) ? v.w : expm1f(v.w);
    f16x4 oh, ol;
    oh[0] = (_Float16)v.x; ol[0] = (_Float16)(v.x - (float)oh[0]);
    oh[1] = (_Float16)v.y; ol[1] = (_Float16)(v.y - (float)oh[1]);
    oh[2] = (_Float16)v.z; ol[2] = (_Float16)(v.z - (float)oh[2]);
    oh[3] = (_Float16)v.w; ol[3] = (_Float16)(v.w - (float)oh[3]);
    *(f16x4*)(Oh + (long)node * NHC + c0) = oh;
    *(f16x4*)(Ol + (long)node * NHC + c0) = ol;
}

// ================= pooling (batch sorted -> contiguous ranges) =================
__global__ __launch_bounds__(256) void hist_kernel(
    const int* __restrict__ batch, int* __restrict__ gcnt, int N)
{
    __shared__ int hist[N_GRAPH];
    if (threadIdx.x < N_GRAPH) hist[threadIdx.x] = 0;
    __syncthreads();
    int i = blockIdx.x * 256 + threadIdx.x;
    if (i < N) atomicAdd(&hist[batch[i]], 1);
    __syncthreads();
    if (threadIdx.x < N_GRAPH && hist[threadIdx.x] > 0)
        atomicAdd(&gcnt[threadIdx.x], hist[threadIdx.x]);
}

__global__ void gstart_kernel(const int* __restrict__ gcnt, int* __restrict__ gstart)
{
    __shared__ int s[N_GRAPH];
    int t = threadIdx.x;
    int v = gcnt[t];
    s[t] = v;
    __syncthreads();
    for (int off = 1; off < N_GRAPH; off <<= 1) {
        int x = (t >= off) ? s[t - off] : 0;
        __syncthreads();
        s[t] += x;
        __syncthreads();
    }
    gstart[t] = s[t] - v;           // exclusive
    if (t == N_GRAPH - 1) gstart[N_GRAPH] = s[t];
}

__global__ __launch_bounds__(256) void pool_reduce_kernel(
    const float* __restrict__ f2, const int* __restrict__ gstart, float* __restrict__ out)
{
    __shared__ float red[8][32];
    int g = blockIdx.x;
    int c = threadIdx.x & 31, rsub = threadIdx.x >> 5;
    int beg = gstart[g], end = gstart[g + 1];
    float acc = 0.f;
    for (int row = beg + rsub; row < end; row += 8)
        acc += f2[(long)row * 32 + c];
    red[rsub][c] = acc;
    __syncthreads();
    if (rsub == 0) {
        float s = red[0][c] + red[1][c] + red[2][c] + red[3][c]
                + red[4][c] + red[5][c] + red[6][c] + red[7][c];
        out[g * 32 + c] = s / fmaxf((float)(end - beg), 1.0f);
    }
}

extern "C" void kernel_launch(void* const* d_in, const int* in_sizes, int n_in,
                              void* d_out, int out_size, void* d_ws, size_t ws_size,
                              hipStream_t stream)
{
    const float* x    = (const float*)d_in[0];
    const int*   ei   = (const int*)  d_in[1];
    const float* ea   = (const float*)d_in[2];
    const int*   bat  = (const int*)  d_in[3];
    const float* W[3]   = {(const float*)d_in[4],  (const float*)d_in[10], (const float*)d_in[16]};
    const float* Asl[3] = {(const float*)d_in[5],  (const float*)d_in[11], (const float*)d_in[17]};
    const float* Adl[3] = {(const float*)d_in[6],  (const float*)d_in[12], (const float*)d_in[18]};
    const float* Wel[3] = {(const float*)d_in[7],  (const float*)d_in[13], (const float*)d_in[19]};
    const float* Ael[3] = {(const float*)d_in[8],  (const float*)d_in[14], (const float*)d_in[20]};
    const float* Bil[3] = {(const float*)d_in[9],  (const float*)d_in[15], (const float*)d_in[21]};
    const float* fcW1 = (const float*)d_in[22];
    const float* fcb1 = (const float*)d_in[23];
    const float* fcW2 = (const float*)d_in[24];
    const float* fcb2 = (const float*)d_in[25];

    // ---- workspace carve (bytes) ----
    char* w = (char*)d_ws;
    float*    h    = (float*)w;        w += (size_t)N_NODES * NHC * 4;   // 51.2MB; reused as f1 planes
    _Float16* xh   = (_Float16*)w;     w += (size_t)N_NODES * DIN * 2;
    _Float16* xl   = (_Float16*)w;     w += (size_t)N_NODES * DIN * 2;
    _Float16* xbh  = (_Float16*)w;     w += (size_t)N_NODES * NHC * 2;   // layer outputs (planes)
    _Float16* xbl  = (_Float16*)w;     w += (size_t)N_NODES * NHC * 2;
    float*    f2   = (float*)w;        w += (size_t)N_NODES * DOUT * 4;
    float*    asb  = (float*)w;        w += (size_t)N_NODES * 8 * 4;
    float*    adb  = (float*)w;        w += (size_t)N_NODES * 8 * 4;
    float*    Me   = (float*)w;        w += 64 * 4;
    _Float16* W1th = (_Float16*)w;     w += (size_t)NHC * DIN * 2;
    _Float16* W1tl = (_Float16*)w;     w += (size_t)NHC * DIN * 2;
    _Float16* W2th = (_Float16*)w;     w += (size_t)NHC * NHC * 2;
    _Float16* W2tl = (_Float16*)w;     w += (size_t)NHC * NHC * 2;
    _Float16* W3th = (_Float16*)w;     w += (size_t)NHC * NHC * 2;
    _Float16* W3tl = (_Float16*)w;     w += (size_t)NHC * NHC * 2;
    _Float16* F1th = (_Float16*)w;     w += (size_t)NHC * NHC * 2;
    _Float16* F1tl = (_Float16*)w;     w += (size_t)NHC * NHC * 2;
    _Float16* F2th = (_Float16*)w;     w += (size_t)64 * NHC * 2;
    _Float16* F2tl = (_Float16*)w;     w += (size_t)64 * NHC * 2;
    int* gcnt     = (int*)w;           w += N_GRAPH * 4;
    int* gstart   = (int*)w;           w += (N_GRAPH + 1) * 4;
    int* deg      = (int*)w;           w += (size_t)N_NODES * 4;
    int* rowstart = (int*)w;           w += (size_t)(N_NODES + 1) * 4;
    int* cursor   = (int*)w;           w += (size_t)N_NODES * 4;
    int* partial  = (int*)w;           w += 256 * 4;
    int* csr_src  = (int*)w;           w += (size_t)N_EDGES * 4;
    int* csr_eid  = (int*)w;           w += (size_t)N_EDGES * 4;
    // f1 planes overlay the (dead-by-then) h buffer
    _Float16* f1h = (_Float16*)h;
    _Float16* f1l = f1h + (size_t)N_NODES * NHC;

    const int NB = (N_NODES + 255) / 256;

    // ---- one-time-per-call prep ----
    split_kernel<<<(N_NODES * DIN / 4 + 255) / 256, 256, 0, stream>>>(x, xh, xl, N_NODES * DIN / 4);
    tsplit_kernel<<<(NHC * DIN + 255) / 256, 256, 0, stream>>>(W[0], W1th, W1tl, DIN, NHC, NHC);
    tsplit_kernel<<<(NHC * NHC + 255) / 256, 256, 0, stream>>>(W[1], W2th, W2tl, NHC, NHC, NHC);
    tsplit_kernel<<<(NHC * NHC + 255) / 256, 256, 0, stream>>>(W[2], W3th, W3tl, NHC, NHC, NHC);
    tsplit_kernel<<<(NHC * NHC + 255) / 256, 256, 0, stream>>>(fcW1, F1th, F1tl, NHC, NHC, NHC);
    tsplit_kernel<<<(64 * NHC + 255) / 256, 256, 0, stream>>>(fcW2, F2th, F2tl, NHC, DOUT, 64);

    // ---- CSR build ----
    hipMemsetAsync(deg, 0, (size_t)N_NODES * 4, stream);
    count_kernel<<<(N_EDGES + 255) / 256, 256, 0, stream>>>(ei, deg, N_EDGES);
    scan_block_kernel<<<NB, 256, 0, stream>>>(deg, rowstart, partial, N_NODES);
    scan_partial_kernel<<<1, 256, 0, stream>>>(partial, NB);
    scan_add_kernel<<<NB, 256, 0, stream>>>(rowstart, partial, cursor, N_NODES, N_EDGES);
    fill_kernel<<<(N_EDGES + 255) / 256, 256, 0, stream>>>(ei, cursor, csr_src, csr_eid, N_EDGES);

    // ---- graph ranges for pooling ----
    hipMemsetAsync(gcnt, 0, N_GRAPH * 4, stream);
    hist_kernel<<<NB, 256, 0, stream>>>(bat, gcnt, N_NODES);
    gstart_kernel<<<1, N_GRAPH, 0, stream>>>(gcnt, gstart);

    const int Hs[3] = {8, 8, 1};
    const int Cs[3] = {32, 32, 256};
    const int CL[3] = {5, 5, 8};
    const int Ks[3] = {DIN, NHC, NHC};

    const dim3 ggrid(NHC / 64, (N_NODES + 127) / 128);

    const _Float16* curh = xh;
    const _Float16* curl = xl;
    const _Float16* Wth[3] = {W1th, W2th, W3th};
    const _Float16* Wtl[3] = {W1tl, W2tl, W3tl};
    for (int l = 0; l < 3; l++) {
        const int H = Hs[l], C = Cs[l];
        const int nh = N_NODES * H;
        mfma_gemm_kernel<<<ggrid, 256, 0, stream>>>(
            curh, curl, Wth[l], Wtl[l], nullptr, h, nullptr, nullptr,
            N_NODES, Ks[l], NHC, 0);
        asd_kernel<<<(nh + 255) / 256, 256, 0, stream>>>(h, Asl[l], Adl[l], asb, adb, nh, H, C);
        me_kernel<<<1, 64, 0, stream>>>(Wel[l], Ael[l], Me, H, C);
        gat_agg_kernel<<<(N_NODES + 3) / 4, 256, 0, stream>>>(
            rowstart, csr_src, csr_eid, ea, asb, adb, Me, h, Bil[l], xbh, xbl, H, CL[l]);
        curh = xbh; curl = xbl;
    }

    // fc1: gelu(xb @ fcW1 + b) -> f1 planes (into h region; h is dead)
    mfma_gemm_kernel<<<ggrid, 256, 0, stream>>>(
        xbh, xbl, F1th, F1tl, fcb1, nullptr, f1h, f1l, N_NODES, NHC, NHC, 1);
    // fc2: f1 @ fcW2 + b -> f2 fp32 (cols masked to 32)
    const dim3 g2(1, (N_NODES + 127) / 128);
    mfma_gemm_kernel<<<g2, 256, 0, stream>>>(
        f1h, f1l, F2th, F2tl, fcb2, f2, nullptr, nullptr, N_NODES, NHC, DOUT, 2);

    // pooling
    pool_reduce_kernel<<<N_GRAPH, 256, 0, stream>>>(f2, gstart, (float*)d_out);
}

// Round 4
// 752.247 us; speedup vs baseline: 7.5067x; 1.1019x over previous
//
#include <hip/hip_runtime.h>
#include <math.h>

// GATNet_MLP R4: R3 + (a) XCD-aware GEMM swizzle (col-tiles of one row-block
// stay on one XCD's L2), (b) LDS pad 32->40 halfs (kills b128 bank conflicts),
// (c) edge-parallel p precompute (removes 64x-redundant expf from gat_agg).

#define N_NODES 50000
#define N_EDGES 400000
#define N_GRAPH 64
#define DIN     128
#define NHC     256
#define DOUT    32

typedef _Float16 f16x8 __attribute__((ext_vector_type(8)));
typedef _Float16 f16x4 __attribute__((ext_vector_type(4)));
typedef float    f32x4 __attribute__((ext_vector_type(4)));

#define LDP 40   // padded LDS row stride in halfs (80B = 20 banks; period-8 covers all 32)

// ================= fp16x2-split MFMA GEMM =================
// mode 0: C fp32 [nrow][256] (no bias) ; mode 1: bias+gelu -> fp16 planes ;
// mode 2: bias -> fp32 C [nrow][ncols]
__global__ __launch_bounds__(256) void mfma_gemm_kernel(
    const _Float16* __restrict__ Ah, const _Float16* __restrict__ Al,
    const _Float16* __restrict__ Bh, const _Float16* __restrict__ Bl,
    const float* __restrict__ bias, float* __restrict__ C,
    _Float16* __restrict__ Oh, _Float16* __restrict__ Ol,
    int nrow, int K, int ncols, int mode)
{
    __shared__ __align__(16) _Float16 sAh[128][LDP];
    __shared__ __align__(16) _Float16 sAl[128][LDP];
    __shared__ __align__(16) _Float16 sBh[64][LDP];
    __shared__ __align__(16) _Float16 sBl[64][LDP];

    const int tid = threadIdx.x, lane = tid & 63, wid = tid >> 6;
    const int wm = wid & 1, wn = wid >> 1;

    // XCD-aware swizzle (gridX==4 path): bids k,k+8,k+16,k+24 (same XCD mod-8)
    // are the 4 col-tiles of row-block yt -> A row-block stays in that XCD's L2.
    int xt, yt;
    if (gridDim.x == 4) {
        int bid = blockIdx.x + (blockIdx.y << 2);
        yt = (bid >> 5) * 8 + (bid & 7);
        xt = (bid >> 3) & 3;
    } else { xt = blockIdx.x; yt = blockIdx.y; }
    const int row0 = yt * 128, col0 = xt * 64;
    if (row0 >= nrow) return;                 // uniform across block (padded grid)

    const int rs = lane >> 2, kq = lane & 3;
    const int frow = lane & 15, fk = (lane >> 4) * 8;

    f32x4 acc[4][2] = {};

    for (int k0 = 0; k0 < K; k0 += 32) {
#pragma unroll
        for (int p = 0; p < 2; p++) {
            int r = p * 64 + wid * 16 + rs;
            int gr = row0 + r;
            long go = (long)gr * K + k0 + kq * 8;
            f16x8 vh = (gr < nrow) ? *(const f16x8*)(Ah + go) : (f16x8)0;
            f16x8 vl = (gr < nrow) ? *(const f16x8*)(Al + go) : (f16x8)0;
            *(f16x8*)&sAh[r][kq * 8] = vh;
            *(f16x8*)&sAl[r][kq * 8] = vl;
        }
        {
            int n = wid * 16 + rs;
            long go = (long)(col0 + n) * K + k0 + kq * 8;
            *(f16x8*)&sBh[n][kq * 8] = *(const f16x8*)(Bh + go);
            *(f16x8*)&sBl[n][kq * 8] = *(const f16x8*)(Bl + go);
        }
        __syncthreads();

        f16x8 bh[2], bl[2];
#pragma unroll
        for (int nt = 0; nt < 2; nt++) {
            bh[nt] = *(const f16x8*)&sBh[wn * 32 + nt * 16 + frow][fk];
            bl[nt] = *(const f16x8*)&sBl[wn * 32 + nt * 16 + frow][fk];
        }
#pragma unroll
        for (int mt = 0; mt < 4; mt++) {
            f16x8 ah = *(const f16x8*)&sAh[wm * 64 + mt * 16 + frow][fk];
            f16x8 al = *(const f16x8*)&sAl[wm * 64 + mt * 16 + frow][fk];
#pragma unroll
            for (int nt = 0; nt < 2; nt++) {
                acc[mt][nt] = __builtin_amdgcn_mfma_f32_16x16x32_f16(ah, bh[nt], acc[mt][nt], 0, 0, 0);
                acc[mt][nt] = __builtin_amdgcn_mfma_f32_16x16x32_f16(ah, bl[nt], acc[mt][nt], 0, 0, 0);
                acc[mt][nt] = __builtin_amdgcn_mfma_f32_16x16x32_f16(al, bh[nt], acc[mt][nt], 0, 0, 0);
            }
        }
        __syncthreads();
    }

    // epilogue: C/D layout col=lane&15, row=(lane>>4)*4+reg
    const int crow0 = row0 + wm * 64 + (lane >> 4) * 4;
    const int ccol0 = col0 + wn * 32 + (lane & 15);
#pragma unroll
    for (int mt = 0; mt < 4; mt++) {
#pragma unroll
        for (int nt = 0; nt < 2; nt++) {
            int col = ccol0 + nt * 16;
#pragma unroll
            for (int r = 0; r < 4; r++) {
                int row = crow0 + mt * 16 + r;
                if (row >= nrow) continue;
                float v = acc[mt][nt][r];
                if (mode == 0) {
                    C[(long)row * 256 + col] = v;
                } else if (mode == 1) {
                    v += bias[col];
                    v = 0.5f * v * (1.f + erff(v * 0.7071067811865475f));
                    _Float16 hh = (_Float16)v;
                    Oh[(long)row * 256 + col] = hh;
                    Ol[(long)row * 256 + col] = (_Float16)(v - (float)hh);
                } else {
                    if (col < ncols) {
                        v += bias[col];
                        C[(long)row * ncols + col] = v;
                    }
                }
            }
        }
    }
}

// -------- split fp32 -> fp16 hi/lo planes --------
__global__ __launch_bounds__(256) void split_kernel(
    const float* __restrict__ in, _Float16* __restrict__ oh, _Float16* __restrict__ ol, int n4)
{
    int i = blockIdx.x * 256 + threadIdx.x;
    if (i >= n4) return;
    float4 v = ((const float4*)in)[i];
    f16x4 h, l;
    h[0] = (_Float16)v.x; l[0] = (_Float16)(v.x - (float)h[0]);
    h[1] = (_Float16)v.y; l[1] = (_Float16)(v.y - (float)h[1]);
    h[2] = (_Float16)v.z; l[2] = (_Float16)(v.z - (float)h[2]);
    h[3] = (_Float16)v.w; l[3] = (_Float16)(v.w - (float)h[3]);
    *(f16x4*)(oh + (long)i * 4) = h;
    *(f16x4*)(ol + (long)i * 4) = l;
}

// -------- transpose + split weights: W[K][N] fp32 -> planes [Npad][K] --------
__global__ __launch_bounds__(256) void tsplit_kernel(
    const float* __restrict__ W, _Float16* __restrict__ Bh, _Float16* __restrict__ Bl,
    int K, int N, int Npad)
{
    int id = blockIdx.x * 256 + threadIdx.x;
    if (id >= Npad * K) return;
    int n = id / K, k = id - n * K;
    float v = (n < N) ? W[(long)k * N + n] : 0.f;
    _Float16 h = (_Float16)v;
    Bh[id] = h;
    Bl[id] = (_Float16)(v - (float)h);
}

// -------- per-node attention scalars --------
__global__ __launch_bounds__(256) void asd_kernel(
    const float* __restrict__ h, const float* __restrict__ atts, const float* __restrict__ attd,
    float* __restrict__ asb, float* __restrict__ adb, int total, int H, int C)
{
    int i = blockIdx.x * 256 + threadIdx.x;
    if (i >= total) return;
    int n = i / H, hh = i - n * H;
    const float4* hp = (const float4*)(h + (long)n * NHC + hh * C);
    const float4* sp = (const float4*)(atts + hh * C);
    const float4* dp = (const float4*)(attd + hh * C);
    float ss = 0.f, dd = 0.f;
    for (int c = 0; c < C / 4; c++) {
        float4 hv = hp[c], sv = sp[c], dv = dp[c];
        ss += hv.x * sv.x + hv.y * sv.y + hv.z * sv.z + hv.w * sv.w;
        dd += hv.x * dv.x + hv.y * dv.y + hv.z * dv.z + hv.w * dv.w;
    }
    asb[i] = ss; adb[i] = dd;
}

// -------- Me[j,h] = sum_c We[j, h*C+c] * ae[h*C+c] --------
__global__ void me_kernel(const float* __restrict__ We, const float* __restrict__ ae,
                          float* __restrict__ Me, int H, int C)
{
    int i = threadIdx.x;
    if (i >= 5 * H) return;
    int j = i / H, hh = i - j * H;
    float s = 0.f;
    for (int c = 0; c < C; c++) s += We[j * NHC + hh * C + c] * ae[hh * C + c];
    Me[i] = s;
}

// -------- edge-parallel p: p[e,h] = exp(leaky(a_s[src]+a_d[dst]+a_e)) --------
__global__ __launch_bounds__(256) void edge_p_kernel(
    const int* __restrict__ ei, const float* __restrict__ ea,
    const float* __restrict__ asb, const float* __restrict__ adb,
    const float* __restrict__ Me, float* __restrict__ p, int E, int H)
{
    int e = blockIdx.x * 256 + threadIdx.x;
    if (e >= E) return;
    int src = ei[e], dst = ei[E + e];
    float a0 = ea[e * 5 + 0], a1 = ea[e * 5 + 1], a2 = ea[e * 5 + 2],
          a3 = ea[e * 5 + 3], a4 = ea[e * 5 + 4];
    for (int h = 0; h < H; h++) {
        float aeh = a0 * Me[0 * H + h] + a1 * Me[1 * H + h] + a2 * Me[2 * H + h]
                  + a3 * Me[3 * H + h] + a4 * Me[4 * H + h];
        float al = asb[src * H + h] + adb[dst * H + h] + aeh;
        al = fmaxf(al, 0.2f * al);
        p[(long)e * H + h] = expf(al);
    }
}

// ================= CSR build =================
__global__ __launch_bounds__(256) void count_kernel(
    const int* __restrict__ ei, int* __restrict__ deg, int E)
{
    int e = blockIdx.x * 256 + threadIdx.x;
    if (e < E) atomicAdd(&deg[ei[E + e]], 1);
}

__global__ __launch_bounds__(256) void scan_block_kernel(
    const int* __restrict__ deg, int* __restrict__ rowstart, int* __restrict__ partial, int n)
{
    __shared__ int s[256];
    int i = blockIdx.x * 256 + threadIdx.x;
    int v = (i < n) ? deg[i] : 0;
    s[threadIdx.x] = v;
    __syncthreads();
    for (int off = 1; off < 256; off <<= 1) {
        int t = (threadIdx.x >= off) ? s[threadIdx.x - off] : 0;
        __syncthreads();
        s[threadIdx.x] += t;
        __syncthreads();
    }
    if (i < n) rowstart[i] = s[threadIdx.x] - v;
    if (threadIdx.x == 255) partial[blockIdx.x] = s[255];
}

__global__ __launch_bounds__(256) void scan_partial_kernel(int* __restrict__ partial, int nb)
{
    __shared__ int s[256];
    int v = (threadIdx.x < nb) ? partial[threadIdx.x] : 0;
    s[threadIdx.x] = v;
    __syncthreads();
    for (int off = 1; off < 256; off <<= 1) {
        int t = (threadIdx.x >= off) ? s[threadIdx.x - off] : 0;
        __syncthreads();
        s[threadIdx.x] += t;
        __syncthreads();
    }
    if (threadIdx.x < nb) partial[threadIdx.x] = s[threadIdx.x] - v;
}

__global__ __launch_bounds__(256) void scan_add_kernel(
    int* __restrict__ rowstart, const int* __restrict__ partial, int* __restrict__ cursor,
    int n, int E)
{
    int i = blockIdx.x * 256 + threadIdx.x;
    if (i < n) {
        int v = rowstart[i] + partial[blockIdx.x];
        rowstart[i] = v;
        cursor[i] = v;
    }
    if (i == 0) rowstart[n] = E;
}

__global__ __launch_bounds__(256) void fill_kernel(
    const int* __restrict__ ei, int* __restrict__ cursor,
    int* __restrict__ csr_src, int* __restrict__ csr_eid, int E)
{
    int e = blockIdx.x * 256 + threadIdx.x;
    if (e >= E) return;
    int dst = ei[E + e];
    int pos = atomicAdd(&cursor[dst], 1);
    csr_src[pos] = ei[e];
    csr_eid[pos] = e;
}

// ========== fused GAT aggregation (p precomputed) -> fp16 planes ==========
__global__ __launch_bounds__(256) void gat_agg_kernel(
    const int* __restrict__ rowstart, const int* __restrict__ csr_src, const int* __restrict__ csr_eid,
    const float* __restrict__ p, const float* __restrict__ h, const float* __restrict__ bias,
    _Float16* __restrict__ Oh, _Float16* __restrict__ Ol, int H, int clog2)
{
    int node = blockIdx.x * 4 + (threadIdx.x >> 6);
    if (node >= N_NODES) return;
    int lane = threadIdx.x & 63;
    int c0 = lane * 4;
    int head = c0 >> clog2;
    int beg = rowstart[node], end = rowstart[node + 1];
    float ax = 0.f, ay = 0.f, az = 0.f, aw = 0.f, den = 0.f;
    for (int i = beg; i < end; i++) {
        int src = csr_src[i];
        int eid = csr_eid[i];
        float pv = p[(long)eid * H + head];
        den += pv;
        const float4 hv = *(const float4*)(h + (long)src * NHC + c0);
        ax += pv * hv.x; ay += pv * hv.y; az += pv * hv.z; aw += pv * hv.w;
    }
    float w = 1.0f / (den + 1e-16f);
    const float4 bv = *(const float4*)(bias + c0);
    float4 v;
    v.x = ax * w + bv.x;  v.y = ay * w + bv.y;
    v.z = az * w + bv.z;  v.w = aw * w + bv.w;
    v.x = (v.x > 0.f) ? v.x : expm1f(v.x);
    v.y = (v.y > 0.f) ? v.y : expm1f(v.y);
    v.z = (v.z > 0.f) ? v.z : expm1f(v.z);
    v.w = (v.w > 0.f) ? v.w : expm1f(v.w);
    f16x4 oh, ol;
    oh[0] = (_Float16)v.x; ol[0] = (_Float16)(v.x - (float)oh[0]);
    oh[1] = (_Float16)v.y; ol[1] = (_Float16)(v.y - (float)oh[1]);
    oh[2] = (_Float16)v.z; ol[2] = (_Float16)(v.z - (float)oh[2]);
    oh[3] = (_Float16)v.w; ol[3] = (_Float16)(v.w - (float)oh[3]);
    *(f16x4*)(Oh + (long)node * NHC + c0) = oh;
    *(f16x4*)(Ol + (long)node * NHC + c0) = ol;
}

// ================= pooling (batch sorted) =================
__global__ __launch_bounds__(256) void hist_kernel(
    const int* __restrict__ batch, int* __restrict__ gcnt, int N)
{
    __shared__ int hist[N_GRAPH];
    if (threadIdx.x < N_GRAPH) hist[threadIdx.x] = 0;
    __syncthreads();
    int i = blockIdx.x * 256 + threadIdx.x;
    if (i < N) atomicAdd(&hist[batch[i]], 1);
    __syncthreads();
    if (threadIdx.x < N_GRAPH && hist[threadIdx.x] > 0)
        atomicAdd(&gcnt[threadIdx.x], hist[threadIdx.x]);
}

__global__ void gstart_kernel(const int* __restrict__ gcnt, int* __restrict__ gstart)
{
    __shared__ int s[N_GRAPH];
    int t = threadIdx.x;
    int v = gcnt[t];
    s[t] = v;
    __syncthreads();
    for (int off = 1; off < N_GRAPH; off <<= 1) {
        int x = (t >= off) ? s[t - off] : 0;
        __syncthreads();
        s[t] += x;
        __syncthreads();
    }
    gstart[t] = s[t] - v;
    if (t == N_GRAPH - 1) gstart[N_GRAPH] = s[t];
}

__global__ __launch_bounds__(256) void pool_reduce_kernel(
    const float* __restrict__ f2, const int* __restrict__ gstart, float* __restrict__ out)
{
    __shared__ float red[8][32];
    int g = blockIdx.x;
    int c = threadIdx.x & 31, rsub = threadIdx.x >> 5;
    int beg = gstart[g], end = gstart[g + 1];
    float acc = 0.f;
    for (int row = beg + rsub; row < end; row += 8)
        acc += f2[(long)row * 32 + c];
    red[rsub][c] = acc;
    __syncthreads();
    if (rsub == 0) {
        float s = red[0][c] + red[1][c] + red[2][c] + red[3][c]
                + red[4][c] + red[5][c] + red[6][c] + red[7][c];
        out[g * 32 + c] = s / fmaxf((float)(end - beg), 1.0f);
    }
}

extern "C" void kernel_launch(void* const* d_in, const int* in_sizes, int n_in,
                              void* d_out, int out_size, void* d_ws, size_t ws_size,
                              hipStream_t stream)
{
    const float* x    = (const float*)d_in[0];
    const int*   ei   = (const int*)  d_in[1];
    const float* ea   = (const float*)d_in[2];
    const int*   bat  = (const int*)  d_in[3];
    const float* W[3]   = {(const float*)d_in[4],  (const float*)d_in[10], (const float*)d_in[16]};
    const float* Asl[3] = {(const float*)d_in[5],  (const float*)d_in[11], (const float*)d_in[17]};
    const float* Adl[3] = {(const float*)d_in[6],  (const float*)d_in[12], (const float*)d_in[18]};
    const float* Wel[3] = {(const float*)d_in[7],  (const float*)d_in[13], (const float*)d_in[19]};
    const float* Ael[3] = {(const float*)d_in[8],  (const float*)d_in[14], (const float*)d_in[20]};
    const float* Bil[3] = {(const float*)d_in[9],  (const float*)d_in[15], (const float*)d_in[21]};
    const float* fcW1 = (const float*)d_in[22];
    const float* fcb1 = (const float*)d_in[23];
    const float* fcW2 = (const float*)d_in[24];
    const float* fcb2 = (const float*)d_in[25];

    // ---- workspace carve (bytes) ----
    char* w = (char*)d_ws;
    float*    h    = (float*)w;        w += (size_t)N_NODES * NHC * 4;   // reused as f1 planes
    _Float16* xh   = (_Float16*)w;     w += (size_t)N_NODES * DIN * 2;
    _Float16* xl   = (_Float16*)w;     w += (size_t)N_NODES * DIN * 2;
    _Float16* xbh  = (_Float16*)w;     w += (size_t)N_NODES * NHC * 2;
    _Float16* xbl  = (_Float16*)w;     w += (size_t)N_NODES * NHC * 2;
    float*    f2   = (float*)w;        w += (size_t)N_NODES * DOUT * 4;
    float*    asb  = (float*)w;        w += (size_t)N_NODES * 8 * 4;
    float*    adb  = (float*)w;        w += (size_t)N_NODES * 8 * 4;
    float*    pbuf = (float*)w;        w += (size_t)N_EDGES * 8 * 4;
    float*    Me   = (float*)w;        w += 64 * 4;
    _Float16* W1th = (_Float16*)w;     w += (size_t)NHC * DIN * 2;
    _Float16* W1tl = (_Float16*)w;     w += (size_t)NHC * DIN * 2;
    _Float16* W2th = (_Float16*)w;     w += (size_t)NHC * NHC * 2;
    _Float16* W2tl = (_Float16*)w;     w += (size_t)NHC * NHC * 2;
    _Float16* W3th = (_Float16*)w;     w += (size_t)NHC * NHC * 2;
    _Float16* W3tl = (_Float16*)w;     w += (size_t)NHC * NHC * 2;
    _Float16* F1th = (_Float16*)w;     w += (size_t)NHC * NHC * 2;
    _Float16* F1tl = (_Float16*)w;     w += (size_t)NHC * NHC * 2;
    _Float16* F2th = (_Float16*)w;     w += (size_t)64 * NHC * 2;
    _Float16* F2tl = (_Float16*)w;     w += (size_t)64 * NHC * 2;
    int* gcnt     = (int*)w;           w += N_GRAPH * 4;
    int* gstart   = (int*)w;           w += (N_GRAPH + 1) * 4;
    int* deg      = (int*)w;           w += (size_t)N_NODES * 4;
    int* rowstart = (int*)w;           w += (size_t)(N_NODES + 1) * 4;
    int* cursor   = (int*)w;           w += (size_t)N_NODES * 4;
    int* partial  = (int*)w;           w += 256 * 4;
    int* csr_src  = (int*)w;           w += (size_t)N_EDGES * 4;
    int* csr_eid  = (int*)w;           w += (size_t)N_EDGES * 4;
    _Float16* f1h = (_Float16*)h;
    _Float16* f1l = f1h + (size_t)N_NODES * NHC;

    const int NB = (N_NODES + 255) / 256;

    // ---- prep: splits ----
    split_kernel<<<(N_NODES * DIN / 4 + 255) / 256, 256, 0, stream>>>(x, xh, xl, N_NODES * DIN / 4);
    tsplit_kernel<<<(NHC * DIN + 255) / 256, 256, 0, stream>>>(W[0], W1th, W1tl, DIN, NHC, NHC);
    tsplit_kernel<<<(NHC * NHC + 255) / 256, 256, 0, stream>>>(W[1], W2th, W2tl, NHC, NHC, NHC);
    tsplit_kernel<<<(NHC * NHC + 255) / 256, 256, 0, stream>>>(W[2], W3th, W3tl, NHC, NHC, NHC);
    tsplit_kernel<<<(NHC * NHC + 255) / 256, 256, 0, stream>>>(fcW1, F1th, F1tl, NHC, NHC, NHC);
    tsplit_kernel<<<(64 * NHC + 255) / 256, 256, 0, stream>>>(fcW2, F2th, F2tl, NHC, DOUT, 64);

    // ---- CSR build ----
    hipMemsetAsync(deg, 0, (size_t)N_NODES * 4, stream);
    count_kernel<<<(N_EDGES + 255) / 256, 256, 0, stream>>>(ei, deg, N_EDGES);
    scan_block_kernel<<<NB, 256, 0, stream>>>(deg, rowstart, partial, N_NODES);
    scan_partial_kernel<<<1, 256, 0, stream>>>(partial, NB);
    scan_add_kernel<<<NB, 256, 0, stream>>>(rowstart, partial, cursor, N_NODES, N_EDGES);
    fill_kernel<<<(N_EDGES + 255) / 256, 256, 0, stream>>>(ei, cursor, csr_src, csr_eid, N_EDGES);

    // ---- graph ranges for pooling ----
    hipMemsetAsync(gcnt, 0, N_GRAPH * 4, stream);
    hist_kernel<<<NB, 256, 0, stream>>>(bat, gcnt, N_NODES);
    gstart_kernel<<<1, N_GRAPH, 0, stream>>>(gcnt, gstart);

    const int Hs[3] = {8, 8, 1};
    const int Cs[3] = {32, 32, 256};
    const int CL[3] = {5, 5, 8};
    const int Ks[3] = {DIN, NHC, NHC};

    const dim3 ggrid(4, 392);               // Y padded to %8 for the swizzle bijection

    const _Float16* curh = xh;
    const _Float16* curl = xl;
    const _Float16* Wth[3] = {W1th, W2th, W3th};
    const _Float16* Wtl[3] = {W1tl, W2tl, W3tl};
    for (int l = 0; l < 3; l++) {
        const int H = Hs[l], C = Cs[l];
        const int nh = N_NODES * H;
        mfma_gemm_kernel<<<ggrid, 256, 0, stream>>>(
            curh, curl, Wth[l], Wtl[l], nullptr, h, nullptr, nullptr,
            N_NODES, Ks[l], NHC, 0);
        asd_kernel<<<(nh + 255) / 256, 256, 0, stream>>>(h, Asl[l], Adl[l], asb, adb, nh, H, C);
        me_kernel<<<1, 64, 0, stream>>>(Wel[l], Ael[l], Me, H, C);
        edge_p_kernel<<<(N_EDGES + 255) / 256, 256, 0, stream>>>(ei, ea, asb, adb, Me, pbuf, N_EDGES, H);
        gat_agg_kernel<<<(N_NODES + 3) / 4, 256, 0, stream>>>(
            rowstart, csr_src, csr_eid, pbuf, h, Bil[l], xbh, xbl, H, CL[l]);
        curh = xbh; curl = xbl;
    }

    // fc1: gelu(xb @ fcW1 + b) -> f1 planes (overlays dead h)
    mfma_gemm_kernel<<<ggrid, 256, 0, stream>>>(
        xbh, xbl, F1th, F1tl, fcb1, nullptr, f1h, f1l, N_NODES, NHC, NHC, 1);
    // fc2: f1 @ fcW2 + b -> f2 fp32 (cols masked to 32)
    const dim3 g2(1, (N_NODES + 127) / 128);
    mfma_gemm_kernel<<<g2, 256, 0, stream>>>(
        f1h, f1l, F2th, F2tl, fcb2, f2, nullptr, nullptr, N_NODES, NHC, DOUT, 2);

    // pooling
    pool_reduce_kernel<<<N_GRAPH, 256, 0, stream>>>(f2, gstart, (float*)d_out);
}